// Round 1
// baseline (520.618 us; speedup 1.0000x reference)
//
#include <hip/hip_runtime.h>
#include <hip/hip_bf16.h>
#include <stdint.h>

#define NTOK 4096   // B*T = 2*2048
#define CD   1024
#define HD   4096
#define NE   8

typedef __attribute__((ext_vector_type(8))) short bf16x8;
typedef __attribute__((ext_vector_type(4))) float f32x4;
typedef __attribute__((ext_vector_type(4))) unsigned short us4;

__device__ __forceinline__ unsigned short f2bf(float f){
  __hip_bfloat16 h = __float2bfloat16(f);
  return *reinterpret_cast<unsigned short*>(&h);
}

// ---------------- router: logits (fp64 accum), softmax, top-2, renorm; x -> bf16 ----------------
__global__ __launch_bounds__(256) void router_kernel(
    const float* __restrict__ x, const float* __restrict__ rw,
    unsigned short* __restrict__ x_bf, int* __restrict__ top_i,
    float* __restrict__ top_w, int* __restrict__ counts){
  __shared__ float rw_lds[NE*CD];
  int tid = threadIdx.x;
  for (int i = tid; i < NE*CD/4; i += 256)
    ((float4*)rw_lds)[i] = ((const float4*)rw)[i];
  __syncthreads();
  int l = tid & 63, w = tid >> 6;
  int n = blockIdx.x*4 + w;

  float4 xv[4];
  #pragma unroll
  for (int j = 0; j < 4; ++j)
    xv[j] = ((const float4*)(x + (size_t)n*CD))[l + j*64];

  #pragma unroll
  for (int j = 0; j < 4; ++j){
    us4 o; o.x = f2bf(xv[j].x); o.y = f2bf(xv[j].y); o.z = f2bf(xv[j].z); o.w = f2bf(xv[j].w);
    *(us4*)(x_bf + (size_t)n*CD + l*4 + j*256) = o;
  }

  double le[NE];
  #pragma unroll
  for (int e = 0; e < NE; ++e){
    double p = 0.0;
    #pragma unroll
    for (int j = 0; j < 4; ++j){
      float4 rv = ((const float4*)(rw_lds + e*CD))[l + j*64];
      p += (double)xv[j].x*rv.x + (double)xv[j].y*rv.y + (double)xv[j].z*rv.z + (double)xv[j].w*rv.w;
    }
    #pragma unroll
    for (int d = 32; d >= 1; d >>= 1) p += __shfl_xor(p, d);
    le[e] = p;
  }
  if (l == 0){
    double m = le[0];
    #pragma unroll
    for (int e = 1; e < NE; ++e) m = le[e] > m ? le[e] : m;
    double pe[NE], s = 0.0;
    #pragma unroll
    for (int e = 0; e < NE; ++e){ pe[e] = exp(le[e]-m); s += pe[e]; }
    (void)s;
    int i0 = 0;
    #pragma unroll
    for (int e = 1; e < NE; ++e) if (pe[e] > pe[i0]) i0 = e;     // strict > : ties -> lower idx (matches lax.top_k)
    int i1 = (i0 == 0) ? 1 : 0;
    #pragma unroll
    for (int e = 0; e < NE; ++e){ if (e == i0) continue; if (pe[e] > pe[i1]) i1 = e; }
    double w0 = pe[i0], w1v = pe[i1], wsum = w0 + w1v;
    top_i[2*n] = i0; top_i[2*n+1] = i1;
    top_w[2*n] = (float)(w0/wsum); top_w[2*n+1] = (float)(w1v/wsum);
    atomicAdd(&counts[i0], 1); atomicAdd(&counts[i1], 1);
  }
}

// ---------------- tiny scan: 8-entry exclusive prefix ----------------
__global__ void scan_kernel(const int* __restrict__ counts, int* __restrict__ offsets, int* __restrict__ cursor){
  if (threadIdx.x == 0){
    int s = 0;
    for (int e = 0; e < NE; ++e){ offsets[e] = s; cursor[e] = s; s += counts[e]; }
  }
}

// ---------------- scatter tokens into expert-grouped lists ----------------
__global__ __launch_bounds__(256) void scatter_kernel(
    const int* __restrict__ top_i, const float* __restrict__ top_w,
    int* __restrict__ cursor, int* __restrict__ g_tok, float* __restrict__ g_w){
  int n = blockIdx.x*256 + threadIdx.x;
  #pragma unroll
  for (int k = 0; k < 2; ++k){
    int e = top_i[2*n+k];
    int pos = atomicAdd(&cursor[e], 1);
    g_tok[pos] = n;
    g_w[pos] = top_w[2*n+k];
  }
}

// ---------------- weight transpose + fp32->bf16: in [R][S] -> out [S][R], per expert ----------------
template<int R, int S>
__global__ __launch_bounds__(256) void transpose_cvt(const float* __restrict__ in, unsigned short* __restrict__ outp){
  __shared__ float tile[64][65];
  int e = blockIdx.z;
  const float* ip = in + (size_t)e*R*S;
  unsigned short* op = outp + (size_t)e*R*S;
  int s0 = blockIdx.x*64, r0 = blockIdx.y*64;
  int tid = threadIdx.x;
  #pragma unroll
  for (int i = 0; i < 4; ++i){
    int lin = i*256 + tid;
    int rr = lin >> 4, c4 = lin & 15;
    float4 v = *(const float4*)(ip + (size_t)(r0+rr)*S + s0 + c4*4);
    tile[rr][c4*4+0] = v.x; tile[rr][c4*4+1] = v.y;
    tile[rr][c4*4+2] = v.z; tile[rr][c4*4+3] = v.w;
  }
  __syncthreads();
  #pragma unroll
  for (int i = 0; i < 4; ++i){
    int lin = i*256 + tid;
    int ss = lin >> 4, rq = lin & 15;
    us4 o;
    o.x = f2bf(tile[rq*4+0][ss]);
    o.y = f2bf(tile[rq*4+1][ss]);
    o.z = f2bf(tile[rq*4+2][ss]);
    o.w = f2bf(tile[rq*4+3][ss]);
    *(us4*)(op + (size_t)(s0+ss)*R + r0 + rq*4) = o;
  }
}

// ---------------- grouped GEMM, m97 structure: 128x128 tile, BK=64, 4 waves ----------------
// EPI 0: h = gelu(x @ w1t^T) stored bf16 per-slot.  EPI 1: out[token] += w * (h @ w2t^T), fp32 atomics.
// A stride == KDIM for both (x rows / h rows). B rows per expert = NDIM, stride KDIM.
template<int KDIM, int EPI>
__global__ __launch_bounds__(256) void gemm_grouped(
    const unsigned short* __restrict__ A_src,
    const unsigned short* __restrict__ B_src,
    unsigned short* __restrict__ h_out,
    float* __restrict__ outp,
    const int* __restrict__ g_tok,
    const float* __restrict__ g_w,
    const int* __restrict__ counts,
    const int* __restrict__ offsets,
    int NDIM){
  int e = blockIdx.z;
  int n_e = counts[e];
  int m0 = blockIdx.y*128;
  if (m0 >= n_e) return;
  int n0 = blockIdx.x*128;
  int g_base = offsets[e];

  __shared__ alignas(128) char lds[32768];   // A: [0,16K) , B: [16K,32K)

  int tid = threadIdx.x, l = tid & 63, w = tid >> 6;
  int wr = w >> 1, wc = w & 1;

  // staging: 16 segments of 8 rows x 128B each, per operand; wave w owns segs w*4..w*4+3.
  // linear LDS dest (global_load_lds writes base+lane*16); source chunk pre-swizzled so
  // LDS(row, c) = SRC(row, c ^ (row&7))  -> conflict-free swizzled ds_read later.
  const unsigned short* a_src[4];
  const unsigned short* b_src[4];
  uint32_t a_ldsoff[4], b_ldsoff[4];
  #pragma unroll
  for (int i = 0; i < 4; ++i){
    int s = w*4 + i;
    int row = 8*s + (l >> 3);
    int chunk = (l & 7) ^ (row & 7);
    int rg = m0 + row; if (rg > n_e-1) rg = n_e-1;   // clamp partial tile (rows discarded at epilogue)
    size_t arow;
    if (EPI == 0) arow = (size_t)g_tok[g_base + rg];     // gather token rows of x
    else          arow = (size_t)(g_base + rg);          // dense slot rows of h
    a_src[i] = A_src + arow*(size_t)KDIM + chunk*8;
    b_src[i] = B_src + ((size_t)e*NDIM + n0 + row)*(size_t)KDIM + chunk*8;
    a_ldsoff[i] = s*1024u;
    b_ldsoff[i] = 16384u + s*1024u;
  }

  // fragment read offsets (swizzled): byte = row*128 + 16*((4s+q) ^ (row&7)); s=1 is ^64
  int lrow = l & 15, q = l >> 4;
  uint32_t a_off[4], b_off[4];
  #pragma unroll
  for (int m = 0; m < 4; ++m){
    int rowa = wr*64 + m*16 + lrow;
    a_off[m] = rowa*128 + 16*(q ^ (rowa & 7));
    int rowb = wc*64 + m*16 + lrow;
    b_off[m] = 16384u + rowb*128 + 16*(q ^ (rowb & 7));
  }

  f32x4 acc[4][4] = {};

  for (int k0 = 0; k0 < KDIM; k0 += 64){
    #pragma unroll
    for (int i = 0; i < 4; ++i){
      __builtin_amdgcn_global_load_lds((const __attribute__((address_space(1))) void*)a_src[i],
                                       (__attribute__((address_space(3))) void*)&lds[a_ldsoff[i]], 16, 0, 0);
      a_src[i] += 64;
      __builtin_amdgcn_global_load_lds((const __attribute__((address_space(1))) void*)b_src[i],
                                       (__attribute__((address_space(3))) void*)&lds[b_ldsoff[i]], 16, 0, 0);
      b_src[i] += 64;
    }
    __syncthreads();
    #pragma unroll
    for (int s = 0; s < 2; ++s){
      bf16x8 av[4], bv[4];
      #pragma unroll
      for (int m = 0; m < 4; ++m){
        av[m] = *(const bf16x8*)&lds[a_off[m] ^ (s*64)];
        bv[m] = *(const bf16x8*)&lds[b_off[m] ^ (s*64)];
      }
      #pragma unroll
      for (int m = 0; m < 4; ++m)
        #pragma unroll
        for (int n = 0; n < 4; ++n)
          acc[m][n] = __builtin_amdgcn_mfma_f32_16x16x32_bf16(av[m], bv[n], acc[m][n], 0, 0, 0);
    }
    __syncthreads();
  }

  // C/D layout (verified m89): col = lane&15, row = (lane>>4)*4 + j
  if (EPI == 0){
    #pragma unroll
    for (int m = 0; m < 4; ++m){
      #pragma unroll
      for (int j = 0; j < 4; ++j){
        int r = m0 + wr*64 + m*16 + q*4 + j;
        if (r < n_e){
          unsigned short* hp = h_out + (size_t)(g_base + r)*NDIM + n0 + wc*64 + lrow;
          #pragma unroll
          for (int n = 0; n < 4; ++n){
            float v = acc[m][n][j];
            v = 0.5f*v*(1.0f + erff(v*0.70710678118654752f));   // exact GELU
            hp[n*16] = f2bf(v);
          }
        }
      }
    }
  } else {
    #pragma unroll
    for (int m = 0; m < 4; ++m){
      #pragma unroll
      for (int j = 0; j < 4; ++j){
        int r = m0 + wr*64 + m*16 + q*4 + j;
        if (r < n_e){
          int slot = g_base + r;
          int t = g_tok[slot];
          float wgt = g_w[slot];
          float* op = outp + (size_t)t*NDIM + n0 + wc*64 + lrow;
          #pragma unroll
          for (int n = 0; n < 4; ++n)
            atomicAdd(op + n*16, wgt*acc[m][n][j]);
        }
      }
    }
  }
}

extern "C" void kernel_launch(void* const* d_in, const int* in_sizes, int n_in,
                              void* d_out, int out_size, void* d_ws, size_t ws_size,
                              hipStream_t stream) {
  const float* x  = (const float*)d_in[0];
  const float* rw = (const float*)d_in[1];
  const float* w1 = (const float*)d_in[2];
  const float* w2 = (const float*)d_in[3];

  size_t off = 0;
  auto alloc = [&](size_t sz) -> char* {
    char* p = (char*)d_ws + off;
    off += (sz + 255) & ~(size_t)255;
    return p;
  };
  unsigned short* x_bf = (unsigned short*)alloc((size_t)NTOK*CD*2);   // 8.4 MB
  unsigned short* w1t  = (unsigned short*)alloc((size_t)NE*CD*HD*2);  // 67 MB  [E][H][C]
  unsigned short* w2t  = (unsigned short*)alloc((size_t)NE*CD*HD*2);  // 67 MB  [E][C][H]
  unsigned short* hbuf = (unsigned short*)alloc((size_t)NTOK*2*HD*2); // 67 MB  [slot][H]
  int*   top_i  = (int*)alloc(NTOK*2*4);
  float* top_w  = (float*)alloc(NTOK*2*4);
  int*   counts = (int*)alloc(64);
  int*   offs   = (int*)alloc(64);
  int*   cursor = (int*)alloc(64);
  int*   g_tok  = (int*)alloc(NTOK*2*4);
  float* g_w    = (float*)alloc(NTOK*2*4);
  (void)ws_size; (void)in_sizes; (void)n_in; (void)out_size;

  hipMemsetAsync(d_out, 0, (size_t)NTOK*CD*4, stream);
  hipMemsetAsync(counts, 0, 64, stream);

  router_kernel<<<dim3(NTOK/4), dim3(256), 0, stream>>>(x, rw, x_bf, top_i, top_w, counts);
  scan_kernel<<<dim3(1), dim3(64), 0, stream>>>(counts, offs, cursor);
  scatter_kernel<<<dim3(NTOK/256), dim3(256), 0, stream>>>(top_i, top_w, cursor, g_tok, g_w);

  transpose_cvt<CD, HD><<<dim3(HD/64, CD/64, NE), dim3(256), 0, stream>>>(w1, w1t);
  transpose_cvt<HD, CD><<<dim3(CD/64, HD/64, NE), dim3(256), 0, stream>>>(w2, w2t);

  // GEMM1: h = gelu(x @ w1t^T)   M=n_e, N=H (4096), K=C (1024)
  gemm_grouped<CD, 0><<<dim3(HD/128, 32, NE), dim3(256), 0, stream>>>(
      x_bf, w1t, hbuf, (float*)nullptr, g_tok, g_w, counts, offs, HD);
  // GEMM2: out[token] += w * (h @ w2t^T)   M=n_e, N=C (1024), K=H (4096)
  gemm_grouped<HD, 1><<<dim3(CD/128, 32, NE), dim3(256), 0, stream>>>(
      hbuf, w2t, (unsigned short*)nullptr, (float*)d_out, g_tok, g_w, counts, offs, CD);
}

// Round 2
// 484.741 us; speedup vs baseline: 1.0740x; 1.0740x over previous
//
#include <hip/hip_runtime.h>
#include <hip/hip_bf16.h>
#include <stdint.h>

#define NTOK 4096   // B*T = 2*2048
#define CD   1024
#define HD   4096
#define NE   8

typedef __attribute__((ext_vector_type(8))) short bf16x8;
typedef __attribute__((ext_vector_type(4))) float f32x4;
typedef __attribute__((ext_vector_type(4))) unsigned short us4;

__device__ __forceinline__ unsigned short f2bf(float f){
  __hip_bfloat16 h = __float2bfloat16(f);
  return *reinterpret_cast<unsigned short*>(&h);
}

// ---------------- router: logits (fp64 accum), softmax, top-2, renorm; x -> bf16 ----------------
__global__ __launch_bounds__(256) void router_kernel(
    const float* __restrict__ x, const float* __restrict__ rw,
    unsigned short* __restrict__ x_bf, int* __restrict__ top_i,
    float* __restrict__ top_w, int* __restrict__ counts){
  __shared__ float rw_lds[NE*CD];
  int tid = threadIdx.x;
  for (int i = tid; i < NE*CD/4; i += 256)
    ((float4*)rw_lds)[i] = ((const float4*)rw)[i];
  __syncthreads();
  int l = tid & 63, w = tid >> 6;
  int n = blockIdx.x*4 + w;

  float4 xv[4];
  #pragma unroll
  for (int j = 0; j < 4; ++j)
    xv[j] = ((const float4*)(x + (size_t)n*CD))[l + j*64];

  #pragma unroll
  for (int j = 0; j < 4; ++j){
    us4 o; o.x = f2bf(xv[j].x); o.y = f2bf(xv[j].y); o.z = f2bf(xv[j].z); o.w = f2bf(xv[j].w);
    *(us4*)(x_bf + (size_t)n*CD + l*4 + j*256) = o;
  }

  double le[NE];
  #pragma unroll
  for (int e = 0; e < NE; ++e){
    double p = 0.0;
    #pragma unroll
    for (int j = 0; j < 4; ++j){
      float4 rv = ((const float4*)(rw_lds + e*CD))[l + j*64];
      p += (double)xv[j].x*rv.x + (double)xv[j].y*rv.y + (double)xv[j].z*rv.z + (double)xv[j].w*rv.w;
    }
    #pragma unroll
    for (int d = 32; d >= 1; d >>= 1) p += __shfl_xor(p, d);
    le[e] = p;
  }
  if (l == 0){
    double m = le[0];
    #pragma unroll
    for (int e = 1; e < NE; ++e) m = le[e] > m ? le[e] : m;
    double pe[NE], s = 0.0;
    #pragma unroll
    for (int e = 0; e < NE; ++e){ pe[e] = exp(le[e]-m); s += pe[e]; }
    (void)s;
    int i0 = 0;
    #pragma unroll
    for (int e = 1; e < NE; ++e) if (pe[e] > pe[i0]) i0 = e;     // strict > : ties -> lower idx (matches lax.top_k)
    int i1 = (i0 == 0) ? 1 : 0;
    #pragma unroll
    for (int e = 0; e < NE; ++e){ if (e == i0) continue; if (pe[e] > pe[i1]) i1 = e; }
    double w0 = pe[i0], w1v = pe[i1], wsum = w0 + w1v;
    top_i[2*n] = i0; top_i[2*n+1] = i1;
    top_w[2*n] = (float)(w0/wsum); top_w[2*n+1] = (float)(w1v/wsum);
    atomicAdd(&counts[i0], 1); atomicAdd(&counts[i1], 1);
  }
}

// ---------------- tiny scan: 8-entry exclusive prefix ----------------
__global__ void scan_kernel(const int* __restrict__ counts, int* __restrict__ offsets, int* __restrict__ cursor){
  if (threadIdx.x == 0){
    int s = 0;
    for (int e = 0; e < NE; ++e){ offsets[e] = s; cursor[e] = s; s += counts[e]; }
  }
}

// ---------------- scatter tokens into expert-grouped lists ----------------
__global__ __launch_bounds__(256) void scatter_kernel(
    const int* __restrict__ top_i, const float* __restrict__ top_w,
    int* __restrict__ cursor, int* __restrict__ g_tok, float* __restrict__ g_w){
  int n = blockIdx.x*256 + threadIdx.x;
  #pragma unroll
  for (int k = 0; k < 2; ++k){
    int e = top_i[2*n+k];
    int pos = atomicAdd(&cursor[e], 1);
    g_tok[pos] = n;
    g_w[pos] = top_w[2*n+k];
  }
}

// ---------------- weight transpose + fp32->bf16: in [R][S] -> out [S][R], per expert ----------------
template<int R, int S>
__global__ __launch_bounds__(256) void transpose_cvt(const float* __restrict__ in, unsigned short* __restrict__ outp){
  __shared__ float tile[64][65];
  int e = blockIdx.z;
  const float* ip = in + (size_t)e*R*S;
  unsigned short* op = outp + (size_t)e*R*S;
  int s0 = blockIdx.x*64, r0 = blockIdx.y*64;
  int tid = threadIdx.x;
  #pragma unroll
  for (int i = 0; i < 4; ++i){
    int lin = i*256 + tid;
    int rr = lin >> 4, c4 = lin & 15;
    float4 v = *(const float4*)(ip + (size_t)(r0+rr)*S + s0 + c4*4);
    tile[rr][c4*4+0] = v.x; tile[rr][c4*4+1] = v.y;
    tile[rr][c4*4+2] = v.z; tile[rr][c4*4+3] = v.w;
  }
  __syncthreads();
  #pragma unroll
  for (int i = 0; i < 4; ++i){
    int lin = i*256 + tid;
    int ss = lin >> 4, rq = lin & 15;
    us4 o;
    o.x = f2bf(tile[rq*4+0][ss]);
    o.y = f2bf(tile[rq*4+1][ss]);
    o.z = f2bf(tile[rq*4+2][ss]);
    o.w = f2bf(tile[rq*4+3][ss]);
    *(us4*)(op + (size_t)(s0+ss)*R + r0 + rq*4) = o;
  }
}

// ---------------- grouped GEMM, 2-phase double-buffered (T3 minimal recipe) ----------------
// 128x128 tile, BK=64, 4 waves (2x2, per-wave 64x64), 64KB LDS dbuf -> 2 blocks/CU.
// Per iter: STAGE next K-tile into buf^1 -> ds_read buf -> MFMA (setprio) -> one barrier.
// EPI 0: h = gelu(x @ w1t^T) stored bf16 per-slot.  EPI 1: out[token] += w * (h @ w2t^T), fp32 atomics.
template<int KDIM, int EPI>
__global__ __launch_bounds__(256, 2) void gemm2ph(
    const unsigned short* __restrict__ A_src,
    const unsigned short* __restrict__ B_src,
    unsigned short* __restrict__ h_out,
    float* __restrict__ outp,
    const int* __restrict__ g_tok,
    const float* __restrict__ g_w,
    const int* __restrict__ counts,
    const int* __restrict__ offsets,
    int NDIM){
  constexpr int NT = KDIM/64;
  __shared__ alignas(128) char lds[65536];   // buf b at b*32768: A [0,16K) B [16K,32K)

  int e = blockIdx.z;
  int n_e = counts[e];
  int m0 = blockIdx.y*128;
  if (m0 >= n_e) return;
  int n0 = blockIdx.x*128;
  int g_base = offsets[e];

  int tid = threadIdx.x, l = tid & 63, w = tid >> 6;
  int wr = w >> 1, wc = w & 1;
  int lrow = l & 15, q = l >> 4;

  // staging: 32 segments (16 A + 16 B) of 8 rows x 128B; each wave owns 8.
  // linear LDS dest (global_load_lds writes base+lane*16); source chunk pre-swizzled so
  // LDS(row, p) = SRC(row, p ^ (row&7))  -> conflict-free swizzled ds_read.
  const unsigned short* src[8];
  uint32_t dst[8];
  #pragma unroll
  for (int i = 0; i < 8; ++i){
    int s = w*8 + i;                    // 0..31
    bool isA = s < 16;
    int srow = (s & 15)*8 + (l >> 3);
    int chunk = (l & 7) ^ (srow & 7);
    if (isA){
      int rg = m0 + srow; if (rg > n_e-1) rg = n_e-1;   // clamp partial tile (rows discarded at epilogue)
      size_t arow;
      if (EPI == 0) arow = (size_t)g_tok[g_base + rg];  // gather token rows of x
      else          arow = (size_t)(g_base + rg);       // dense slot rows of h
      src[i] = A_src + arow*(size_t)KDIM + chunk*8;
    } else {
      src[i] = B_src + ((size_t)e*NDIM + n0 + srow)*(size_t)KDIM + chunk*8;
    }
    dst[i] = (isA ? 0u : 16384u) + (uint32_t)(s & 15)*1024u;
  }

  // fragment read offsets (swizzled): byte = row*128 + 16*((q + 4*ks) ^ (row&7)); ks=1 is ^64
  uint32_t a_off[4], b_off[4];
  #pragma unroll
  for (int m = 0; m < 4; ++m){
    int ra = wr*64 + m*16 + lrow;
    a_off[m] = ra*128 + 16*(q ^ (ra & 7));
    int rb = wc*64 + m*16 + lrow;
    b_off[m] = 16384u + rb*128 + 16*(q ^ (rb & 7));
  }

  f32x4 acc[4][4] = {};

  // prologue: stage K-tile 0 into buf 0
  #pragma unroll
  for (int i = 0; i < 8; ++i){
    __builtin_amdgcn_global_load_lds((const __attribute__((address_space(1))) void*)src[i],
                                     (__attribute__((address_space(3))) void*)&lds[dst[i]], 16, 0, 0);
    src[i] += 64;
  }
  __syncthreads();

  uint32_t buf = 0;
  for (int kt = 0; kt < NT; ++kt){
    if (kt + 1 < NT){
      uint32_t nb = (buf ^ 1)*32768u;
      #pragma unroll
      for (int i = 0; i < 8; ++i){
        __builtin_amdgcn_global_load_lds((const __attribute__((address_space(1))) void*)src[i],
                                         (__attribute__((address_space(3))) void*)&lds[dst[i] + nb], 16, 0, 0);
        src[i] += 64;
      }
    }
    uint32_t ro = buf*32768u;
    #pragma unroll
    for (int ks = 0; ks < 2; ++ks){
      bf16x8 av[4], bv[4];
      #pragma unroll
      for (int m = 0; m < 4; ++m){
        av[m] = *(const bf16x8*)&lds[(a_off[m] ^ (ks*64)) + ro];
        bv[m] = *(const bf16x8*)&lds[(b_off[m] ^ (ks*64)) + ro];
      }
      __builtin_amdgcn_s_setprio(1);
      #pragma unroll
      for (int m = 0; m < 4; ++m)
        #pragma unroll
        for (int n = 0; n < 4; ++n)
          acc[m][n] = __builtin_amdgcn_mfma_f32_16x16x32_bf16(av[m], bv[n], acc[m][n], 0, 0, 0);
      __builtin_amdgcn_s_setprio(0);
    }
    __syncthreads();   // drains vmcnt (prefetch done) + lgkmcnt; buf^1 now safe to read, buf safe to overwrite
    buf ^= 1;
  }

  // C/D layout (verified m89): col = lane&15, row = (lane>>4)*4 + j
  if (EPI == 0){
    #pragma unroll
    for (int m = 0; m < 4; ++m){
      #pragma unroll
      for (int j = 0; j < 4; ++j){
        int r = m0 + wr*64 + m*16 + q*4 + j;
        if (r < n_e){
          unsigned short* hp = h_out + (size_t)(g_base + r)*NDIM + n0 + wc*64 + lrow;
          #pragma unroll
          for (int n = 0; n < 4; ++n){
            float v = acc[m][n][j];
            v = 0.5f*v*(1.0f + erff(v*0.70710678118654752f));   // exact GELU
            hp[n*16] = f2bf(v);
          }
        }
      }
    }
  } else {
    #pragma unroll
    for (int m = 0; m < 4; ++m){
      #pragma unroll
      for (int j = 0; j < 4; ++j){
        int r = m0 + wr*64 + m*16 + q*4 + j;
        if (r < n_e){
          int slot = g_base + r;
          int t = g_tok[slot];
          float wgt = g_w[slot];
          float* op = outp + (size_t)t*NDIM + n0 + wc*64 + lrow;
          #pragma unroll
          for (int n = 0; n < 4; ++n)
            atomicAdd(op + n*16, wgt*acc[m][n][j]);
        }
      }
    }
  }
}

extern "C" void kernel_launch(void* const* d_in, const int* in_sizes, int n_in,
                              void* d_out, int out_size, void* d_ws, size_t ws_size,
                              hipStream_t stream) {
  const float* x  = (const float*)d_in[0];
  const float* rw = (const float*)d_in[1];
  const float* w1 = (const float*)d_in[2];
  const float* w2 = (const float*)d_in[3];

  size_t off = 0;
  auto alloc = [&](size_t sz) -> char* {
    char* p = (char*)d_ws + off;
    off += (sz + 255) & ~(size_t)255;
    return p;
  };
  unsigned short* x_bf = (unsigned short*)alloc((size_t)NTOK*CD*2);   // 8.4 MB
  unsigned short* w1t  = (unsigned short*)alloc((size_t)NE*CD*HD*2);  // 67 MB  [E][H][C]
  unsigned short* w2t  = (unsigned short*)alloc((size_t)NE*CD*HD*2);  // 67 MB  [E][C][H]
  unsigned short* hbuf = (unsigned short*)alloc((size_t)NTOK*2*HD*2); // 67 MB  [slot][H]
  int*   top_i  = (int*)alloc(NTOK*2*4);
  float* top_w  = (float*)alloc(NTOK*2*4);
  int*   counts = (int*)alloc(64);
  int*   offs   = (int*)alloc(64);
  int*   cursor = (int*)alloc(64);
  int*   g_tok  = (int*)alloc(NTOK*2*4);
  float* g_w    = (float*)alloc(NTOK*2*4);
  (void)ws_size; (void)in_sizes; (void)n_in; (void)out_size;

  hipMemsetAsync(d_out, 0, (size_t)NTOK*CD*4, stream);
  hipMemsetAsync(counts, 0, 64, stream);

  router_kernel<<<dim3(NTOK/4), dim3(256), 0, stream>>>(x, rw, x_bf, top_i, top_w, counts);
  scan_kernel<<<dim3(1), dim3(64), 0, stream>>>(counts, offs, cursor);
  scatter_kernel<<<dim3(NTOK/256), dim3(256), 0, stream>>>(top_i, top_w, cursor, g_tok, g_w);

  transpose_cvt<CD, HD><<<dim3(HD/64, CD/64, NE), dim3(256), 0, stream>>>(w1, w1t);
  transpose_cvt<HD, CD><<<dim3(CD/64, HD/64, NE), dim3(256), 0, stream>>>(w2, w2t);

  // GEMM1: h = gelu(x @ w1t^T)   M=n_e, N=H (4096), K=C (1024)
  gemm2ph<CD, 0><<<dim3(HD/128, 32, NE), dim3(256), 0, stream>>>(
      x_bf, w1t, hbuf, (float*)nullptr, g_tok, g_w, counts, offs, HD);
  // GEMM2: out[token] += w * (h @ w2t^T)   M=n_e, N=C (1024), K=H (4096)
  gemm2ph<HD, 1><<<dim3(CD/128, 32, NE), dim3(256), 0, stream>>>(
      hbuf, w2t, (unsigned short*)nullptr, (float*)d_out, g_tok, g_w, counts, offs, CD);
}